// Round 10
// baseline (246.433 us; speedup 1.0000x reference)
//
#include <hip/hip_runtime.h>

// UpSampling3D x2 trilinear, align_corners=True.
// x [64,48,48,48] f32 -> y [64,96,96,96] f32
// pos(o) = 47*o/95; weights (1-fr, fr) at (floor, floor+1); norm (1/(1+1e-6))^3
// (norm^3 folded into the r-blend stage weights; all axes linear => exact).
//
// R9 = R6 + (a) nontemporal stores via native ext_vector (writes bypass L2 ->
// L2 kept for the 4x-reused input planes), (b) statically unrolled stage loop.
//  - one block per output plane (bh, r_out); stage r-blended plane into
//    LDS P[48][52] (9.8 KB -> 8 blocks/CU); ONE barrier.
//  - compute: thread -> (c, d-group of 4); LDS reads mostly broadcast/2-way;
//    select-based d-blend (static reg indices); contiguous float4 nt stores.
//  - bijective XCD-chunked swizzle (6144 = 8 x 768): plane re-reads hit the
//    XCD-private L2.

#define IN_N      48
#define RS_IN     (48*48)      // 2304
#define BH_IN     (48*48*48)   // 110592
#define OUT_N     96
#define PLANE_OUT (96*96)      // 9216
#define PADW      52           // padded LDS row width

typedef float v4f __attribute__((ext_vector_type(4)));

__global__ __launch_bounds__(256, 8) void up3d_kernel(const float* __restrict__ x,
                                                      float* __restrict__ y) {
    __shared__ float P[IN_N * PADW];   // 9984 B

    const int tid = threadIdx.x;
    // XCD-chunked bijective swizzle: 6144 blocks = 8 XCDs x 768
    const int fid = blockIdx.x;
    const int swz = (fid & 7) * 768 + (fid >> 3);
    const int r_out = swz % 96;
    const int bh    = swz / 96;

    const int t47 = 47 * r_out;
    const int r0  = t47 / 95;
    const int r1  = min(r0 + 1, IN_N - 1);          // r_out=95 -> fr=0, clamp safe
    const float fr = (float)(t47 - 95 * r0) * (1.0f / 95.0f);
    const float n1 = 1.0f / (1.0f + 1e-6f);
    const float n3 = n1 * n1 * n1;
    const float wa = (1.0f - fr) * n3;
    const float wb = fr * n3;

    const float* pA = x + (size_t)bh * BH_IN + (size_t)r0 * RS_IN;
    const float* pB = x + (size_t)bh * BH_IN + (size_t)r1 * RS_IN;

    // ---- stage: r-blended plane -> LDS (static 3-iter unroll, coalesced) ----
    #pragma unroll
    for (int j = 0; j < 3; ++j) {
        const int i = tid + j * 256;                // 576 = 2*256 + 64
        if (j < 2 || tid < 64) {
            const int c = i / 12, k = i % 12;
            v4f a = *reinterpret_cast<const v4f*>(pA + c * IN_N + 4 * k);
            v4f b = *reinterpret_cast<const v4f*>(pB + c * IN_N + 4 * k);
            v4f v = wa * a + wb * b;
            *reinterpret_cast<v4f*>(&P[c * PADW + 4 * k]) = v;
        }
    }
    if (tid < IN_N) {                                // zero pad cols 48..51 (window overrun, weight 0)
        *reinterpret_cast<v4f*>(&P[tid * PADW + 48]) = (v4f)(0.0f);
    }
    __syncthreads();

    float* yb = y + (size_t)swz * PLANE_OUT;         // swz == bh*96 + r_out

    #pragma unroll
    for (int it = 0; it < 9; ++it) {                 // 9*256 = 2304 float4 = full plane
        const int idx = it * 256 + tid;
        const int dg = idx % 24;                     // d-group (4 outputs along d)
        const int c  = idx / 24;                     // output col 0..95

        const int tc = 47 * c;
        const int c0 = tc / 95;
        const int c1 = min(c0 + 1, IN_N - 1);
        const float wc1 = (float)(tc - 95 * c0) * (1.0f / 95.0f);
        const float wc0 = 1.0f - wc1;

        const int td  = 188 * dg;                    // 47*(4*dg)
        const int dlo = td / 95;                     // window start (covers all 4 d)
        const int rm0 = td - 95 * dlo;

        const float* rowA = &P[c0 * PADW + dlo];
        const float* rowB = &P[c1 * PADW + dlo];
        const float f0 = wc0 * rowA[0] + wc1 * rowB[0];
        const float f1 = wc0 * rowA[1] + wc1 * rowB[1];
        const float f2 = wc0 * rowA[2] + wc1 * rowB[2];
        const float f3 = wc0 * rowA[3] + wc1 * rowB[3];

        v4f o;
        #pragma unroll
        for (int i = 0; i < 4; ++i) {
            const int s = rm0 + 47 * i;              // 95*delta + rem
            const int delta = (s >= 95 ? 1 : 0) + (s >= 190 ? 1 : 0);   // 0..2
            const float fd1 = (float)(s - 95 * delta) * (1.0f / 95.0f);
            const float lo = (delta == 0) ? f0 : ((delta == 1) ? f1 : f2);
            const float hi = (delta == 0) ? f1 : ((delta == 1) ? f2 : f3);
            o[i] = lo + fd1 * (hi - lo);
        }
        // nontemporal: stores bypass L2 (no reuse; keep L2 for input planes)
        __builtin_nontemporal_store(o, reinterpret_cast<v4f*>(yb + 4 * idx));
    }
}

extern "C" void kernel_launch(void* const* d_in, const int* in_sizes, int n_in,
                              void* d_out, int out_size, void* d_ws, size_t ws_size,
                              hipStream_t stream) {
    const float* x = (const float*)d_in[0];
    float* y = (float*)d_out;
    hipLaunchKernelGGL(up3d_kernel, dim3(64 * 96), dim3(256), 0, stream, x, y);
}